// Round 3
// baseline (27.577 us; speedup 1.0000x reference)
//
#include <hip/hip_runtime.h>
#include <math.h>

#define NUM_FIELDS 24
#define VOCAB 100000
#define EMBED_DIM 64
#define BATCH 16384

// One 64-lane wave per TWO batch elements; lane index = embedding dim d.
// Each of the 48 gathers is a coalesced 256B row read (64 lanes x 4B),
// issued nontemporally (single-use lines; keep W_lin/x resident in L2).
__global__ __launch_bounds__(256) void fm_fwd_kernel(
    const int* __restrict__ x,          // [BATCH, NUM_FIELDS]
    const float* __restrict__ W_embed,  // [NUM_FIELDS, VOCAB, EMBED_DIM]
    const float* __restrict__ W_lin,    // [NUM_FIELDS, VOCAB]
    const float* __restrict__ bias,     // [1]
    float* __restrict__ out)            // [BATCH, 1]
{
    const int wave = (int)((blockIdx.x * blockDim.x + threadIdx.x) >> 6);
    const int lane = (int)(threadIdx.x & 63);
    const int b0 = wave * 2;           // handles b0 and b0+1
    if (b0 >= BATCH) return;

    // Indices for both elements: 48 consecutive ints (wave-uniform broadcast loads).
    const int* xb = x + (size_t)b0 * NUM_FIELDS;
    int idx0[NUM_FIELDS], idx1[NUM_FIELDS];
#pragma unroll
    for (int i = 0; i < NUM_FIELDS / 4; ++i) {
        int4 v = reinterpret_cast<const int4*>(xb)[i];
        idx0[4 * i + 0] = v.x; idx0[4 * i + 1] = v.y;
        idx0[4 * i + 2] = v.z; idx0[4 * i + 3] = v.w;
    }
#pragma unroll
    for (int i = 0; i < NUM_FIELDS / 4; ++i) {
        int4 v = reinterpret_cast<const int4*>(xb + NUM_FIELDS)[i];
        idx1[4 * i + 0] = v.x; idx1[4 * i + 1] = v.y;
        idx1[4 * i + 2] = v.z; idx1[4 * i + 3] = v.w;
    }

    // 48 independent gathers, fully unrolled -> max loads in flight.
    float sum0 = 0.f, ssq0 = 0.f;
    float sum1 = 0.f, ssq1 = 0.f;
#pragma unroll
    for (int f = 0; f < NUM_FIELDS; ++f) {
        const float* row0 = W_embed + ((size_t)f * VOCAB + (size_t)idx0[f]) * EMBED_DIM;
        const float* row1 = W_embed + ((size_t)f * VOCAB + (size_t)idx1[f]) * EMBED_DIM;
        float e0 = __builtin_nontemporal_load(row0 + lane);
        float e1 = __builtin_nontemporal_load(row1 + lane);
        sum0 += e0; ssq0 += e0 * e0;
        sum1 += e1; ssq1 += e1 * e1;
    }

    // Per-lane fm contribution; fold first_order (W_lin) into lanes 0..23.
    float v0 = 0.5f * (sum0 * sum0 - ssq0);
    float v1 = 0.5f * (sum1 * sum1 - ssq1);
    if (lane < NUM_FIELDS) {
        v0 += W_lin[(size_t)lane * VOCAB + (size_t)idx0[lane]];
        v1 += W_lin[(size_t)lane * VOCAB + (size_t)idx1[lane]];
    }

    // 64-lane butterfly reductions.
#pragma unroll
    for (int off = 32; off >= 1; off >>= 1) {
        v0 += __shfl_xor(v0, off, 64);
        v1 += __shfl_xor(v1, off, 64);
    }

    if (lane == 0) {
        float b = bias[0];
        float2 r;
        r.x = 1.0f / (1.0f + expf(-(v0 + b)));
        r.y = 1.0f / (1.0f + expf(-(v1 + b)));
        *reinterpret_cast<float2*>(out + b0) = r;
    }
}

extern "C" void kernel_launch(void* const* d_in, const int* in_sizes, int n_in,
                              void* d_out, int out_size, void* d_ws, size_t ws_size,
                              hipStream_t stream) {
    const int*   x       = (const int*)d_in[0];
    const float* W_embed = (const float*)d_in[1];
    const float* W_lin   = (const float*)d_in[2];
    const float* bias    = (const float*)d_in[3];
    float*       out     = (float*)d_out;

    // 2 elements per wave, 4 waves per block -> 8 elements per block.
    const int blocks = BATCH / 8;  // 2048
    fm_fwd_kernel<<<blocks, 256, 0, stream>>>(x, W_embed, W_lin, bias, out);
}

// Round 4
// 27.033 us; speedup vs baseline: 1.0201x; 1.0201x over previous
//
#include <hip/hip_runtime.h>
#include <math.h>

#define NUM_FIELDS 24
#define VOCAB 100000
#define EMBED_DIM 64
#define BATCH 16384

// One 64-lane wave per TWO batch elements; lane = embedding dim d.
// Indices are wave-uniform -> forced into SGPRs via readfirstlane-uniform
// base (s_load), so gathers are SGPR-base + lane*4 voffset: minimal VGPRs,
// full-grid co-residency (32 waves/CU), zero per-lane address VALU.
__global__ __launch_bounds__(256) void fm_fwd_kernel(
    const int* __restrict__ x,          // [BATCH, NUM_FIELDS]
    const float* __restrict__ W_embed,  // [NUM_FIELDS, VOCAB, EMBED_DIM]
    const float* __restrict__ W_lin,    // [NUM_FIELDS, VOCAB]
    const float* __restrict__ bias,     // [1]
    float* __restrict__ out)            // [BATCH, 1]
{
    const int lane = (int)(threadIdx.x & 63);
    const int wave = (int)((blockIdx.x * blockDim.x + threadIdx.x) >> 6);
    const int b0 = wave * 2;
    if (b0 >= BATCH) return;

    // Provably-uniform index base -> scalar loads into SGPRs.
    const int b0u = __builtin_amdgcn_readfirstlane(b0);
    const int* xb = x + (size_t)b0u * NUM_FIELDS;

    int idx[2 * NUM_FIELDS];
#pragma unroll
    for (int i = 0; i < 2 * NUM_FIELDS; ++i) idx[i] = xb[i];

    // Per-lane copy of this lane's own field index for the W_lin gather
    // (runtime-indexing the SGPR array would spill to scratch - rule #20).
    int li0 = 0, li1 = 0;
    if (lane < NUM_FIELDS) {
        li0 = xb[lane];
        li1 = xb[NUM_FIELDS + lane];
    }

    // 48 independent coalesced 256B row gathers, fully unrolled.
    float sum0 = 0.f, ssq0 = 0.f;
    float sum1 = 0.f, ssq1 = 0.f;
#pragma unroll
    for (int f = 0; f < NUM_FIELDS; ++f) {
        float e0 = W_embed[((size_t)f * VOCAB + (size_t)idx[f]) * EMBED_DIM + lane];
        float e1 = W_embed[((size_t)f * VOCAB + (size_t)idx[NUM_FIELDS + f]) * EMBED_DIM + lane];
        sum0 += e0; ssq0 += e0 * e0;
        sum1 += e1; ssq1 += e1 * e1;
    }

    // Per-lane fm contribution; fold first_order (W_lin) into lanes 0..23.
    float v0 = 0.5f * (sum0 * sum0 - ssq0);
    float v1 = 0.5f * (sum1 * sum1 - ssq1);
    if (lane < NUM_FIELDS) {
        v0 += W_lin[(size_t)lane * VOCAB + (size_t)li0];
        v1 += W_lin[(size_t)lane * VOCAB + (size_t)li1];
    }

    // 64-lane butterfly reductions.
#pragma unroll
    for (int off = 32; off >= 1; off >>= 1) {
        v0 += __shfl_xor(v0, off, 64);
        v1 += __shfl_xor(v1, off, 64);
    }

    if (lane == 0) {
        float b = bias[0];
        float2 r;
        r.x = 1.0f / (1.0f + expf(-(v0 + b)));
        r.y = 1.0f / (1.0f + expf(-(v1 + b)));
        *reinterpret_cast<float2*>(out + b0) = r;
    }
}

extern "C" void kernel_launch(void* const* d_in, const int* in_sizes, int n_in,
                              void* d_out, int out_size, void* d_ws, size_t ws_size,
                              hipStream_t stream) {
    const int*   x       = (const int*)d_in[0];
    const float* W_embed = (const float*)d_in[1];
    const float* W_lin   = (const float*)d_in[2];
    const float* bias    = (const float*)d_in[3];
    float*       out     = (float*)d_out;

    // 2 elements per wave, 4 waves per block -> 8 elements per block.
    const int blocks = BATCH / 8;  // 2048
    fm_fwd_kernel<<<blocks, 256, 0, stream>>>(x, W_embed, W_lin, bias, out);
}